// Round 13
// baseline (247.674 us; speedup 1.0000x reference)
//
#include <hip/hip_runtime.h>

typedef __bf16 bf16;
typedef __bf16 bf16x4 __attribute__((ext_vector_type(4)));
typedef __bf16 bf16x8 __attribute__((ext_vector_type(8)));
typedef float  f32x2  __attribute__((ext_vector_type(2)));
typedef float  f32x4  __attribute__((ext_vector_type(4)));
typedef unsigned int u32;
typedef u32 u32x2 __attribute__((ext_vector_type(2)));
typedef u32 u32x4 __attribute__((ext_vector_type(4)));
typedef unsigned short u16;

#define NJ 75
#define SA 104      // A_lds stride (bf16): 208B rows
#define SH 88       // h1 stride: 176B rows; k-overrun killed by A zero-cols
#define SG 136      // gss stride: 272B rows
#define SX 104      // xT stride
#define LN_EPS 1e-5f
#define MFMA16(a,b,c) __builtin_amdgcn_mfma_f32_16x16x32_bf16((a),(b),(c),0,0,0)

static __device__ __forceinline__ f32x4 f4z(){ f32x4 v={0.f,0.f,0.f,0.f}; return v; }
static __device__ __forceinline__ u32 pk2(float a, float b){
  u32 ua = (u32)__builtin_bit_cast(u16,(bf16)a);
  u32 ub = (u32)__builtin_bit_cast(u16,(bf16)b);
  return ua | (ub<<16);
}
static __device__ __forceinline__ float lo16f(u32 u){ return __uint_as_float(u<<16); }
static __device__ __forceinline__ float hi16f(u32 u){ return __uint_as_float(u & 0xffff0000u); }

template<int C>
static __device__ __forceinline__ float dppterm(float v){
  return __int_as_float(__builtin_amdgcn_update_dpp(0, __float_as_int(v), C, 0xF, 0xF, true));
}
static __device__ __forceinline__ float red16(float v){
  v += dppterm<0xB1>(v);
  v += dppterm<0x4E>(v);
  v += dppterm<0x141>(v);
  v += dppterm<0x140>(v);
  return v;
}

// launch_bounds(512,4): caps combined regs at 128 (arch 64 + acc 64) -> 16
// waves/CU with 80KB LDS. Fastest operating point (R7/R11). Do NOT relax.
__global__ __launch_bounds__(512, 4)
void ke12(const float* __restrict__ gx,  const float* __restrict__ gA,
          const float* __restrict__ gW1, const float* __restrict__ gg1, const float* __restrict__ gb1,
          const float* __restrict__ gW2, const float* __restrict__ gg2, const float* __restrict__ gb2,
          const float* __restrict__ gWp, const float* __restrict__ gbp,
          float* __restrict__ gout, int B)
{
  __shared__ __align__(16) bf16 A_lds[80*SA];       // 16,640 B
  __shared__ __align__(16) bf16 h1[128*SH + 16];    // 22,560 B
  __shared__ __align__(16) bf16 gss[80*SG];         // 21,760 B
  __shared__ __align__(16) bf16 xTs[2][4*SX];       //  1,664 B (dbuf)
  __shared__ __align__(16) float red2[16*80*2];     // 10,240 B  [slot][j] f32 (s,q)
  __shared__ __align__(16) float fin[80*2];         //    640 B  (nm, rs)
  __shared__ __align__(16) float skl[3][256];       //  3,072 B
  __shared__ __align__(16) float b1l[128];          //    512 B
  __shared__ __align__(16) u32  g2b2[256];          //  1,024 B
  __shared__ __align__(16) bf16 W1l4[128*4];        //  1,024 B
  __shared__ __align__(16) u32x2 wpl[256];          //  2,048 B
  __shared__ __align__(16) float Msh[12];
  __shared__ float xbars[2][4];

  const int tid = threadIdx.x;
  const int w   = tid >> 6;
  const int l   = tid & 63;
  const int l16 = l & 15;
  const int lg  = l >> 4;

  // ---------------- one-time init ----------------
  for (int i = tid; i < 80*SA; i += 512) {
    const int r = i / SA, c = i - r*SA;
    A_lds[i] = (bf16)((r < NJ && c < NJ) ? gA[r*NJ + c] : 0.f);
  }
  for (int i = tid; i < 128*SH + 16; i += 512) h1[i] = (bf16)0.f;
  for (int i = tid; i < 2*4*SX; i += 512) ((bf16*)xTs)[i] = (bf16)0.f;
  float* wsc = red2;   // init scratch
  if (tid < 128) {
    wsc[tid*3+0] = gW1[tid*3+0];
    wsc[tid*3+1] = gW1[tid*3+1];
    wsc[tid*3+2] = gW1[tid*3+2];
    b1l[tid] = gb1[tid];
    fin[tid] = gg1[tid];          // g1 scratch
  }
  if (tid < 256) {
    g2b2[tid] = pk2(gg2[tid], gb2[tid]);
    u32x2 wv = { pk2(gWp[tid*3+0], gWp[tid*3+1]), pk2(gWp[tid*3+2], gbp[tid]) };
    wpl[tid] = wv;
  }
  __syncthreads();
  if (tid < 3) {
    float s = 0.f;
    for (int c = 0; c < 128; ++c) s += wsc[c*3 + tid];
    Msh[6 + tid] = s * (1.f/128.f);
  }
  __syncthreads();
  if (tid < 128) {
    float wt0 = wsc[tid*3+0] - Msh[6];
    float wt1 = wsc[tid*3+1] - Msh[7];
    float wt2 = wsc[tid*3+2] - Msh[8];
    const float g1v = fin[tid];
    W1l4[tid*4+0] = (bf16)(g1v*wt0);
    W1l4[tid*4+1] = (bf16)(g1v*wt1);
    W1l4[tid*4+2] = (bf16)(g1v*wt2);
    W1l4[tid*4+3] = (bf16)0.f;
    wsc[tid*3+0] = wt0; wsc[tid*3+1] = wt1; wsc[tid*3+2] = wt2;
  }
  __syncthreads();
  if (tid < 6) {
    const int pa[6] = {0,1,2,0,0,1};
    const int pb[6] = {0,1,2,1,2,2};
    float s = 0.f;
    for (int c = 0; c < 128; ++c) s += wsc[c*3 + pa[tid]] * wsc[c*3 + pb[tid]];
    Msh[tid] = s * (1.f/128.f);
  }

  bf16x8 W2fr[2][4];
  #pragma unroll
  for (int ot = 0; ot < 2; ++ot) {
    const int o = 16*(2*w + ot) + l16;
    #pragma unroll
    for (int ks = 0; ks < 4; ++ks) {
      bf16x8 v;
      #pragma unroll
      for (int e = 0; e < 8; ++e) v[e] = (bf16)gW2[o*128 + 32*ks + 8*lg + e];
      W2fr[ot][ks] = v;
    }
  }
  __syncthreads();
  const float M00 = Msh[0], M11 = Msh[1], M22 = Msh[2];
  const float M01 = Msh[3], M02 = Msh[4], M12 = Msh[5];

  const int  fpb  = (B + 511) >> 9;          // grid = 512
  const long base = (long)blockIdx.x * fpb;

  // prologue: wave5 loads + commits frame 0 (slot 0), then issues frame 1
  float xv[4] = {0.f, 0.f, 0.f, 0.f};
  if (w == 5) {
    long fg = base; if (fg >= B) fg = B - 1;
    #pragma unroll
    for (int k = 0; k < 4; ++k) { const int t = l + 64*k; if (t < 225) xv[k] = gx[fg*225 + t]; }
    float s0 = 0.f, s1 = 0.f, s2 = 0.f;
    #pragma unroll
    for (int k = 0; k < 4; ++k) {
      const int t = l + 64*k;
      if (t < 225) {
        const int j = (t*21846) >> 16;   // t/3
        const int co = t - 3*j;
        xTs[0][co*SX + j] = (bf16)xv[k];
        if (co == 0) s0 += xv[k]; else if (co == 1) s1 += xv[k]; else s2 += xv[k];
      }
    }
    s0 = red16(s0); s0 += __shfl_xor(s0, 16); s0 += __shfl_xor(s0, 32);
    s1 = red16(s1); s1 += __shfl_xor(s1, 16); s1 += __shfl_xor(s1, 32);
    s2 = red16(s2); s2 += __shfl_xor(s2, 16); s2 += __shfl_xor(s2, 32);
    if (l == 0) { xbars[0][0] = s0*(1.f/NJ); xbars[0][1] = s1*(1.f/NJ); xbars[0][2] = s2*(1.f/NJ); }
    if (1 < fpb) {
      long f2 = base + 1; if (f2 >= B) f2 = B - 1;
      #pragma unroll
      for (int k = 0; k < 4; ++k) { const int t = l + 64*k; if (t < 225) xv[k] = gx[f2*225 + t]; }
    }
  }
  __syncthreads();

  f32x4 zacc[5][2];
  #pragma unroll
  for (int jt = 0; jt < 5; ++jt) { zacc[jt][0] = f4z(); zacc[jt][1] = f4z(); }

  const int nint = fpb + 2;
  for (int i = 0; i < nint; ++i) {
    // ==================== P1 ====================
    // S_B(i-1): g = A h1'  (c-slice = wave, all 8 waves)
    if (i >= 1 && i <= fpb) {
      const bf16* hb = &h1[(16*w + l16)*SH];
      bf16x8 hf0 = *(const bf16x8*)&hb[ 0 + 8*lg];
      bf16x8 hf1 = *(const bf16x8*)&hb[32 + 8*lg];
      bf16x8 hf2 = *(const bf16x8*)&hb[64 + 8*lg];  // overrun x A zero-cols = 0
      #pragma unroll
      for (int jt = 0; jt < 5; ++jt) {
        const bf16* ab = &A_lds[(16*jt + l16)*SA + 8*lg];
        f32x4 ag = f4z();
        ag = MFMA16(hf0, *(const bf16x8*)&ab[ 0], ag);
        ag = MFMA16(hf1, *(const bf16x8*)&ab[32], ag);
        ag = MFMA16(hf2, *(const bf16x8*)&ab[64], ag);
        bf16x4 p;
        #pragma unroll
        for (int r = 0; r < 4; ++r) p[r] = (bf16)ag[r];
        *(bf16x4*)&gss[(16*jt + l16)*SG + 16*w + 4*lg] = p;
      }
    }
    // waves 6/7: finalize LN2 stats for frame i-2: red2 -> fin
    if (w == 6 && i >= 2) {
      float S = 0.f, Q = 0.f;
      #pragma unroll
      for (int slot = 0; slot < 16; ++slot) {
        const f32x2 a = *(const f32x2*)&red2[(slot*80 + l)*2];
        S += a[0]; Q += a[1];
      }
      const float mu = S * (1.f/256.f);
      const float rs = rsqrtf(Q * (1.f/256.f) - mu*mu + LN_EPS);
      f32x2 nr = { -mu*rs, rs };
      *(f32x2*)&fin[l*2] = nr;
    }
    if (w == 7 && i >= 2 && l < 16) {
      const int j2 = 64 + l;
      float S = 0.f, Q = 0.f;
      #pragma unroll
      for (int slot = 0; slot < 16; ++slot) {
        const f32x2 a = *(const f32x2*)&red2[(slot*80 + j2)*2];
        S += a[0]; Q += a[1];
      }
      const float mu = S * (1.f/256.f);
      const float rs = rsqrtf(Q * (1.f/256.f) - mu*mu + LN_EPS);
      f32x2 nr = { -mu*rs, rs };
      *(f32x2*)&fin[j2*2] = nr;
    }
    __syncthreads();

    // ==================== P2 ====================
    // S_D(i-2): LN2 apply + mean + skip + store
    if (i >= 2) {
      float nmv[5], rsv[5];
      #pragma unroll
      for (int jt = 0; jt < 5; ++jt) {
        const f32x2 nr = *(const f32x2*)&fin[(16*jt + l16)*2];
        nmv[jt] = nr[0]; rsv[jt] = nr[1];
      }
      float os[2][4];
      #pragma unroll
      for (int ot = 0; ot < 2; ++ot) {
        const u32x4 gb = *(const u32x4*)&g2b2[16*(2*w + ot) + 4*lg];
        #pragma unroll
        for (int r = 0; r < 4; ++r) os[ot][r] = 0.f;
        #pragma unroll
        for (int jt = 0; jt < 5; ++jt) {
          #pragma unroll
          for (int r = 0; r < 4; ++r) {
            float v = fmaf(fmaf(zacc[jt][ot][r], rsv[jt], nmv[jt]), lo16f(gb[r]), hi16f(gb[r]));
            v = fmaxf(v, 0.f);
            if (jt == 4) v = (l16 < 11) ? v : 0.f;
            os[ot][r] += v;
          }
        }
        #pragma unroll
        for (int r = 0; r < 4; ++r) os[ot][r] = red16(os[ot][r]);
      }
      const long f = base + (i - 2);
      if (l16 == 0 && f < B) {
        #pragma unroll
        for (int ot = 0; ot < 2; ++ot) {
          const int o0 = 16*(2*w + ot) + 4*lg;
          const f32x4 sk = *(const f32x4*)&skl[(i-2)%3][o0];
          f32x4 res;
          #pragma unroll
          for (int r = 0; r < 4; ++r) res[r] = os[ot][r]*(1.f/NJ) + sk[r];
          *(f32x4*)&gout[f*256 + o0] = res;
        }
      }
    }
    // S_C(i-1): z = W2 g^T (o-slice = wave); xor16 + f32 partials
    if (i >= 1 && i <= fpb) {
      __builtin_amdgcn_s_setprio(1);
      #pragma unroll
      for (int jt = 0; jt < 5; ++jt) {
        const bf16* gr = &gss[(16*jt + l16)*SG + 8*lg];
        f32x4 z0 = f4z(), z1 = f4z();
        #pragma unroll
        for (int ks = 0; ks < 4; ++ks) {
          const bf16x8 gf = *(const bf16x8*)&gr[32*ks];
          z0 = MFMA16(W2fr[0][ks], gf, z0);
          z1 = MFMA16(W2fr[1][ks], gf, z1);
        }
        float s = 0.f, q = 0.f;
        #pragma unroll
        for (int r = 0; r < 4; ++r) {
          s += z0[r] + z1[r];
          q = fmaf(z0[r], z0[r], q); q = fmaf(z1[r], z1[r], q);
        }
        s += __shfl_xor(s, 16); q += __shfl_xor(q, 16);
        if ((lg & 1) == 0) {
          const int slot = 2*w + (lg >> 1);
          f32x2 sq = {s, q};
          *(f32x2*)&red2[(slot*80 + 16*jt + l16)*2] = sq;
        }
        zacc[jt][0] = z0; zacc[jt][1] = z1;
      }
      __builtin_amdgcn_s_setprio(0);
    }
    // S_A(i): x -> h1' (waves 0-4); analytic LN1
    if (i < fpb && w < 5) {
      const int xrow = (l16 < 3) ? l16 : 3;
      const bf16* xb = &xTs[i&1][xrow*SX + 8*lg];
      const bf16* ab = &A_lds[(16*w + l16)*SA + 8*lg];
      f32x4 at = f4z();
      at = MFMA16(*(const bf16x8*)&xb[ 0], *(const bf16x8*)&ab[ 0], at);
      at = MFMA16(*(const bf16x8*)&xb[32], *(const bf16x8*)&ab[32], at);
      at = MFMA16(*(const bf16x8*)&xb[64], *(const bf16x8*)&ab[64], at);
      const float a0 = at[0], a1 = at[1], a2 = at[2];
      float qd = fmaf(M00*a0, a0, fmaf(M11*a1, a1, fmaf(M22*a2, a2, LN_EPS)));
      qd = fmaf(2.f*M01*a0, a1, fmaf(2.f*M02*a0, a2, fmaf(2.f*M12*a1, a2, qd)));
      const float rs = rsqrtf(qd);
      bf16x8 hA;
      #pragma unroll
      for (int e = 0; e < 8; ++e) hA[e] = (bf16)0.f;
      hA[0] = (bf16)((lg == 0) ? a0*rs : 0.f);
      hA[1] = (bf16)((lg == 0) ? a1*rs : 0.f);
      hA[2] = (bf16)((lg == 0) ? a2*rs : 0.f);
      #pragma unroll
      for (int nt = 0; nt < 8; ++nt) {
        const bf16x4 w4 = *(const bf16x4*)&W1l4[(16*nt + l16)*4];
        bf16x8 wb;
        wb[0] = w4[0]; wb[1] = w4[1]; wb[2] = w4[2]; wb[3] = w4[3];
        wb[4] = w4[3]; wb[5] = w4[3]; wb[6] = w4[3]; wb[7] = w4[3];
        const f32x4 hp = MFMA16(hA, wb, f4z());
        const float b1v = b1l[16*nt + l16];
        bf16x4 pkk;
        #pragma unroll
        for (int r = 0; r < 4; ++r) pkk[r] = (bf16)fmaxf(hp[r] + b1v, 0.f);
        *(bf16x4*)&h1[(16*nt + l16)*SH + 16*w + 4*lg] = pkk;
      }
    }
    // wave 5: commit xT(i+1) + xbar(i+1) from regs; issue x(i+2) loads
    if (w == 5 && i + 1 < fpb) {
      const int slot = (i+1) & 1;
      float s0 = 0.f, s1 = 0.f, s2 = 0.f;
      #pragma unroll
      for (int k = 0; k < 4; ++k) {
        const int t = l + 64*k;
        if (t < 225) {
          const int j = (t*21846) >> 16;
          const int co = t - 3*j;
          xTs[slot][co*SX + j] = (bf16)xv[k];
          if (co == 0) s0 += xv[k]; else if (co == 1) s1 += xv[k]; else s2 += xv[k];
        }
      }
      s0 = red16(s0); s0 += __shfl_xor(s0, 16); s0 += __shfl_xor(s0, 32);
      s1 = red16(s1); s1 += __shfl_xor(s1, 16); s1 += __shfl_xor(s1, 32);
      s2 = red16(s2); s2 += __shfl_xor(s2, 16); s2 += __shfl_xor(s2, 32);
      if (l == 0) { xbars[slot][0] = s0*(1.f/NJ); xbars[slot][1] = s1*(1.f/NJ); xbars[slot][2] = s2*(1.f/NJ); }
      if (i + 2 < fpb) {
        long fg = base + i + 2; if (fg >= B) fg = B - 1;
        #pragma unroll
        for (int k = 0; k < 4; ++k) { const int t = l + 64*k; if (t < 225) xv[k] = gx[fg*225 + t]; }
      }
    }
    // wave 6: skip(i)
    if (w == 6 && i < fpb) {
      const float xb0 = xbars[i&1][0], xb1 = xbars[i&1][1], xb2 = xbars[i&1][2];
      #pragma unroll
      for (int k = 0; k < 4; ++k) {
        const int o = l + 64*k;
        const u32x2 wv = wpl[o];
        skl[i%3][o] = fmaf(lo16f(wv[0]), xb0, fmaf(hi16f(wv[0]), xb1, fmaf(lo16f(wv[1]), xb2, hi16f(wv[1]))));
      }
    }
    __syncthreads();
  }
}

extern "C" void kernel_launch(void* const* d_in, const int* in_sizes, int n_in,
                              void* d_out, int out_size, void* d_ws, size_t ws_size,
                              hipStream_t stream) {
  const float* x  = (const float*)d_in[0];
  const float* A  = (const float*)d_in[1];
  const float* W1 = (const float*)d_in[2];
  const float* g1 = (const float*)d_in[3];
  const float* b1 = (const float*)d_in[4];
  const float* W2 = (const float*)d_in[5];
  const float* g2 = (const float*)d_in[6];
  const float* b2 = (const float*)d_in[7];
  const float* Wp = (const float*)d_in[8];
  const float* bp = (const float*)d_in[9];
  float* out = (float*)d_out;
  const int B = in_sizes[0] / 225;
  ke12<<<dim3(512), dim3(512), 0, stream>>>(x, A, W1, g1, b1, W2, g2, b2, Wp, bp, out, B);
}

// Round 14
// 226.955 us; speedup vs baseline: 1.0913x; 1.0913x over previous
//
#include <hip/hip_runtime.h>

typedef __bf16 bf16;
typedef __bf16 bf16x4 __attribute__((ext_vector_type(4)));
typedef __bf16 bf16x8 __attribute__((ext_vector_type(8)));
typedef float  f32x2  __attribute__((ext_vector_type(2)));
typedef float  f32x4  __attribute__((ext_vector_type(4)));
typedef unsigned int u32;
typedef u32 u32x2 __attribute__((ext_vector_type(2)));
typedef u32 u32x4 __attribute__((ext_vector_type(4)));
typedef unsigned short u16;

#define NJ 75
#define SA 104      // A_lds stride (bf16): 208B rows
#define SH 88       // h1 stride: 176B rows; k-overrun killed by A zero-cols
#define SG 136      // gss stride: 272B rows
#define SX 104      // xT stride
#define LN_EPS 1e-5f
#define MFMA16(a,b,c) __builtin_amdgcn_mfma_f32_16x16x32_bf16((a),(b),(c),0,0,0)

static __device__ __forceinline__ f32x4 f4z(){ f32x4 v={0.f,0.f,0.f,0.f}; return v; }
static __device__ __forceinline__ u32 pk2(float a, float b){
  u32 ua = (u32)__builtin_bit_cast(u16,(bf16)a);
  u32 ub = (u32)__builtin_bit_cast(u16,(bf16)b);
  return ua | (ub<<16);
}
static __device__ __forceinline__ float lo16f(u32 u){ return __uint_as_float(u<<16); }
static __device__ __forceinline__ float hi16f(u32 u){ return __uint_as_float(u & 0xffff0000u); }

template<int C>
static __device__ __forceinline__ float dppterm(float v){
  return __int_as_float(__builtin_amdgcn_update_dpp(0, __float_as_int(v), C, 0xF, 0xF, true));
}
static __device__ __forceinline__ float red16(float v){
  v += dppterm<0xB1>(v);
  v += dppterm<0x4E>(v);
  v += dppterm<0x141>(v);
  v += dppterm<0x140>(v);
  return v;
}

// launch_bounds(512,4): caps combined regs at 128 (arch 64 + acc 64) -> 16
// waves/CU with ~80KB LDS. Fastest operating point (R7/R11). Do NOT relax.
__global__ __launch_bounds__(512, 4)
void ke13(const float* __restrict__ gx,  const float* __restrict__ gA,
          const float* __restrict__ gW1, const float* __restrict__ gg1, const float* __restrict__ gb1,
          const float* __restrict__ gW2, const float* __restrict__ gg2, const float* __restrict__ gb2,
          const float* __restrict__ gWp, const float* __restrict__ gbp,
          float* __restrict__ gout, int B)
{
  __shared__ __align__(16) bf16 A_lds[80*SA];       // 16,640 B (row 75 = ones: xbar trick)
  __shared__ __align__(16) bf16 h1[128*SH + 16];    // 22,560 B
  __shared__ __align__(16) bf16 gss[80*SG];         // 21,760 B
  __shared__ __align__(16) bf16 xTs[2][4*SX];       //  1,664 B (dbuf)
  __shared__ __align__(16) float red2[16*80*2];     // 10,240 B  [slot][j] f32 (s,q)
  __shared__ __align__(16) float fin[80*2];         //    640 B  (nm, rs)
  __shared__ __align__(16) float skl[2][256];       //  2,048 B (parity ring)
  __shared__ __align__(16) float b1l[128];          //    512 B
  __shared__ __align__(16) u32  g2b2[256];          //  1,024 B
  __shared__ __align__(16) bf16 W1l4[128*4];        //  1,024 B
  __shared__ __align__(16) u32x2 wpl[256];          //  2,048 B
  __shared__ __align__(16) float Msh[12];
  __shared__ float xbars[2][4];                     // written by w4 lane (0,11) in S_A

  const int tid = threadIdx.x;
  const int w   = tid >> 6;
  const int l   = tid & 63;
  const int l16 = l & 15;
  const int lg  = l >> 4;

  // ---------------- one-time init ----------------
  for (int i = tid; i < 80*SA; i += 512) {
    const int r = i / SA, c = i - r*SA;
    float v = 0.f;
    if (r < NJ && c < NJ) v = gA[r*NJ + c];
    else if (r == 75 && c < NJ) v = 1.f;   // ones-row: at-MFMA emits column sums of x at j=75
    A_lds[i] = (bf16)v;
  }
  for (int i = tid; i < 128*SH + 16; i += 512) h1[i] = (bf16)0.f;
  for (int i = tid; i < 2*4*SX; i += 512) ((bf16*)xTs)[i] = (bf16)0.f;
  float* wsc = red2;   // init scratch
  if (tid < 128) {
    wsc[tid*3+0] = gW1[tid*3+0];
    wsc[tid*3+1] = gW1[tid*3+1];
    wsc[tid*3+2] = gW1[tid*3+2];
    b1l[tid] = gb1[tid];
    fin[tid] = gg1[tid];          // g1 scratch
  }
  if (tid < 256) {
    g2b2[tid] = pk2(gg2[tid], gb2[tid]);
    u32x2 wv = { pk2(gWp[tid*3+0], gWp[tid*3+1]), pk2(gWp[tid*3+2], gbp[tid]) };
    wpl[tid] = wv;
  }
  __syncthreads();
  if (tid < 3) {
    float s = 0.f;
    for (int c = 0; c < 128; ++c) s += wsc[c*3 + tid];
    Msh[6 + tid] = s * (1.f/128.f);
  }
  __syncthreads();
  if (tid < 128) {
    float wt0 = wsc[tid*3+0] - Msh[6];
    float wt1 = wsc[tid*3+1] - Msh[7];
    float wt2 = wsc[tid*3+2] - Msh[8];
    const float g1v = fin[tid];
    W1l4[tid*4+0] = (bf16)(g1v*wt0);
    W1l4[tid*4+1] = (bf16)(g1v*wt1);
    W1l4[tid*4+2] = (bf16)(g1v*wt2);
    W1l4[tid*4+3] = (bf16)0.f;
    wsc[tid*3+0] = wt0; wsc[tid*3+1] = wt1; wsc[tid*3+2] = wt2;
  }
  __syncthreads();
  if (tid < 6) {
    const int pa[6] = {0,1,2,0,0,1};
    const int pb[6] = {0,1,2,1,2,2};
    float s = 0.f;
    for (int c = 0; c < 128; ++c) s += wsc[c*3 + pa[tid]] * wsc[c*3 + pb[tid]];
    Msh[tid] = s * (1.f/128.f);
  }

  bf16x8 W2fr[2][4];
  #pragma unroll
  for (int ot = 0; ot < 2; ++ot) {
    const int o = 16*(2*w + ot) + l16;
    #pragma unroll
    for (int ks = 0; ks < 4; ++ks) {
      bf16x8 v;
      #pragma unroll
      for (int e = 0; e < 8; ++e) v[e] = (bf16)gW2[o*128 + 32*ks + 8*lg + e];
      W2fr[ot][ks] = v;
    }
  }
  __syncthreads();
  const float M00 = Msh[0], M11 = Msh[1], M22 = Msh[2];
  const float M01 = Msh[3], M02 = Msh[4], M12 = Msh[5];

  const int  fpb  = (B + 511) >> 9;          // grid = 512
  const long base = (long)blockIdx.x * fpb;

  // prologue: wave5 loads + commits frame 0 (slot 0), then issues frame 1
  float xv[4] = {0.f, 0.f, 0.f, 0.f};
  if (w == 5) {
    long fg = base; if (fg >= B) fg = B - 1;
    #pragma unroll
    for (int k = 0; k < 4; ++k) { const int t = l + 64*k; if (t < 225) xv[k] = gx[fg*225 + t]; }
    #pragma unroll
    for (int k = 0; k < 4; ++k) {
      const int t = l + 64*k;
      if (t < 225) {
        const int j = (t*21846) >> 16;   // t/3
        const int co = t - 3*j;
        xTs[0][co*SX + j] = (bf16)xv[k];
      }
    }
    if (1 < fpb) {
      long f2 = base + 1; if (f2 >= B) f2 = B - 1;
      #pragma unroll
      for (int k = 0; k < 4; ++k) { const int t = l + 64*k; if (t < 225) xv[k] = gx[f2*225 + t]; }
    }
  }
  __syncthreads();

  f32x4 zacc[5][2];
  #pragma unroll
  for (int jt = 0; jt < 5; ++jt) { zacc[jt][0] = f4z(); zacc[jt][1] = f4z(); }

  const int nint = fpb + 2;
  for (int i = 0; i < nint; ++i) {
    // ==================== P1 ====================
    // S_B(i-1): g = A h1'  (c-slice = wave, all 8 waves)
    if (i >= 1 && i <= fpb) {
      const bf16* hb = &h1[(16*w + l16)*SH];
      bf16x8 hf0 = *(const bf16x8*)&hb[ 0 + 8*lg];
      bf16x8 hf1 = *(const bf16x8*)&hb[32 + 8*lg];
      bf16x8 hf2 = *(const bf16x8*)&hb[64 + 8*lg];  // overrun x A zero-cols = 0
      #pragma unroll
      for (int jt = 0; jt < 5; ++jt) {
        const bf16* ab = &A_lds[(16*jt + l16)*SA + 8*lg];
        f32x4 ag = f4z();
        ag = MFMA16(hf0, *(const bf16x8*)&ab[ 0], ag);
        ag = MFMA16(hf1, *(const bf16x8*)&ab[32], ag);
        ag = MFMA16(hf2, *(const bf16x8*)&ab[64], ag);
        bf16x4 p;
        #pragma unroll
        for (int r = 0; r < 4; ++r) p[r] = (bf16)ag[r];
        *(bf16x4*)&gss[(16*jt + l16)*SG + 16*w + 4*lg] = p;
      }
    }
    // w6 + w7: finalize LN2 stats for frame i-2: red2 -> fin
    if (w == 6 && i >= 2) {
      float S = 0.f, Q = 0.f;
      #pragma unroll
      for (int slot = 0; slot < 16; ++slot) {
        const f32x2 a = *(const f32x2*)&red2[(slot*80 + l)*2];
        S += a[0]; Q += a[1];
      }
      const float mu = S * (1.f/256.f);
      const float rs = rsqrtf(Q * (1.f/256.f) - mu*mu + LN_EPS);
      f32x2 nr = { -mu*rs, rs };
      *(f32x2*)&fin[l*2] = nr;
    }
    if (w == 7 && i >= 2 && l < 16) {
      const int j2 = 64 + l;
      float S = 0.f, Q = 0.f;
      #pragma unroll
      for (int slot = 0; slot < 16; ++slot) {
        const f32x2 a = *(const f32x2*)&red2[(slot*80 + j2)*2];
        S += a[0]; Q += a[1];
      }
      const float mu = S * (1.f/256.f);
      const float rs = rsqrtf(Q * (1.f/256.f) - mu*mu + LN_EPS);
      f32x2 nr = { -mu*rs, rs };
      *(f32x2*)&fin[j2*2] = nr;
    }
    // w7: skip(i-1) from xbars written by S_A(i-1)'s ones-row extraction
    if (w == 7 && i >= 1 && i-1 < fpb) {
      const int sp = (i-1) & 1;
      const float xb0 = xbars[sp][0], xb1 = xbars[sp][1], xb2 = xbars[sp][2];
      #pragma unroll
      for (int k = 0; k < 4; ++k) {
        const int o = l + 64*k;
        const u32x2 wv = wpl[o];
        skl[sp][o] = fmaf(lo16f(wv[0]), xb0, fmaf(hi16f(wv[0]), xb1, fmaf(lo16f(wv[1]), xb2, hi16f(wv[1]))));
      }
    }
    __syncthreads();

    // ==================== P2 ====================
    // S_D(i-2): LN2 apply + mean + skip + store
    if (i >= 2) {
      float nmv[5], rsv[5];
      #pragma unroll
      for (int jt = 0; jt < 5; ++jt) {
        const f32x2 nr = *(const f32x2*)&fin[(16*jt + l16)*2];
        nmv[jt] = nr[0]; rsv[jt] = nr[1];
      }
      float os[2][4];
      #pragma unroll
      for (int ot = 0; ot < 2; ++ot) {
        const u32x4 gb = *(const u32x4*)&g2b2[16*(2*w + ot) + 4*lg];
        #pragma unroll
        for (int r = 0; r < 4; ++r) os[ot][r] = 0.f;
        #pragma unroll
        for (int jt = 0; jt < 5; ++jt) {
          #pragma unroll
          for (int r = 0; r < 4; ++r) {
            float v = fmaf(fmaf(zacc[jt][ot][r], rsv[jt], nmv[jt]), lo16f(gb[r]), hi16f(gb[r]));
            v = fmaxf(v, 0.f);
            if (jt == 4) v = (l16 < 11) ? v : 0.f;
            os[ot][r] += v;
          }
        }
        #pragma unroll
        for (int r = 0; r < 4; ++r) os[ot][r] = red16(os[ot][r]);
      }
      const long f = base + (i - 2);
      if (l16 == 0 && f < B) {
        #pragma unroll
        for (int ot = 0; ot < 2; ++ot) {
          const int o0 = 16*(2*w + ot) + 4*lg;
          const f32x4 sk = *(const f32x4*)&skl[(i-2)&1][o0];
          f32x4 res;
          #pragma unroll
          for (int r = 0; r < 4; ++r) res[r] = os[ot][r]*(1.f/NJ) + sk[r];
          *(f32x4*)&gout[f*256 + o0] = res;
        }
      }
    }
    // S_C(i-1): z = W2 g^T (o-slice = wave); xor16 + f32 partials
    if (i >= 1 && i <= fpb) {
      __builtin_amdgcn_s_setprio(1);
      #pragma unroll
      for (int jt = 0; jt < 5; ++jt) {
        const bf16* gr = &gss[(16*jt + l16)*SG + 8*lg];
        f32x4 z0 = f4z(), z1 = f4z();
        #pragma unroll
        for (int ks = 0; ks < 4; ++ks) {
          const bf16x8 gf = *(const bf16x8*)&gr[32*ks];
          z0 = MFMA16(W2fr[0][ks], gf, z0);
          z1 = MFMA16(W2fr[1][ks], gf, z1);
        }
        float s = 0.f, q = 0.f;
        #pragma unroll
        for (int r = 0; r < 4; ++r) {
          s += z0[r] + z1[r];
          q = fmaf(z0[r], z0[r], q); q = fmaf(z1[r], z1[r], q);
        }
        s += __shfl_xor(s, 16); q += __shfl_xor(q, 16);
        if ((lg & 1) == 0) {
          const int slot = 2*w + (lg >> 1);
          f32x2 sq = {s, q};
          *(f32x2*)&red2[(slot*80 + 16*jt + l16)*2] = sq;
        }
        zacc[jt][0] = z0; zacc[jt][1] = z1;
      }
      __builtin_amdgcn_s_setprio(0);
    }
    // S_A(i): x -> h1' (waves 0-4); analytic LN1; w4 extracts xbar from ones-row
    if (i < fpb && w < 5) {
      const int xrow = (l16 < 3) ? l16 : 3;
      const bf16* xb = &xTs[i&1][xrow*SX + 8*lg];
      const bf16* ab = &A_lds[(16*w + l16)*SA + 8*lg];
      f32x4 at = f4z();
      at = MFMA16(*(const bf16x8*)&xb[ 0], *(const bf16x8*)&ab[ 0], at);
      at = MFMA16(*(const bf16x8*)&xb[32], *(const bf16x8*)&ab[32], at);
      at = MFMA16(*(const bf16x8*)&xb[64], *(const bf16x8*)&ab[64], at);
      // ones-row extraction: wave 4, lane (lg==0,l16==11) holds j=75 = col-sums of x
      if (w == 4 && lg == 0 && l16 == 11) {
        xbars[i&1][0] = at[0] * (1.f/NJ);
        xbars[i&1][1] = at[1] * (1.f/NJ);
        xbars[i&1][2] = at[2] * (1.f/NJ);
      }
      const float a0 = at[0], a1 = at[1], a2 = at[2];
      float qd = fmaf(M00*a0, a0, fmaf(M11*a1, a1, fmaf(M22*a2, a2, LN_EPS)));
      qd = fmaf(2.f*M01*a0, a1, fmaf(2.f*M02*a0, a2, fmaf(2.f*M12*a1, a2, qd)));
      const float rs = rsqrtf(qd);
      bf16x8 hA;
      #pragma unroll
      for (int e = 0; e < 8; ++e) hA[e] = (bf16)0.f;
      hA[0] = (bf16)((lg == 0) ? a0*rs : 0.f);
      hA[1] = (bf16)((lg == 0) ? a1*rs : 0.f);
      hA[2] = (bf16)((lg == 0) ? a2*rs : 0.f);
      #pragma unroll
      for (int nt = 0; nt < 8; ++nt) {
        const bf16x4 w4v = *(const bf16x4*)&W1l4[(16*nt + l16)*4];
        bf16x8 wb;
        wb[0] = w4v[0]; wb[1] = w4v[1]; wb[2] = w4v[2]; wb[3] = w4v[3];
        wb[4] = w4v[3]; wb[5] = w4v[3]; wb[6] = w4v[3]; wb[7] = w4v[3];
        const f32x4 hp = MFMA16(hA, wb, f4z());
        const float b1v = b1l[16*nt + l16];
        bf16x4 pkk;
        #pragma unroll
        for (int r = 0; r < 4; ++r) pkk[r] = (bf16)fmaxf(hp[r] + b1v, 0.f);
        *(bf16x4*)&h1[(16*nt + l16)*SH + 16*w + 4*lg] = pkk;
      }
    }
    // wave 5: commit xT(i+1) (no reductions); issue x(i+2) loads
    if (w == 5 && i + 1 < fpb) {
      const int slot = (i+1) & 1;
      #pragma unroll
      for (int k = 0; k < 4; ++k) {
        const int t = l + 64*k;
        if (t < 225) {
          const int j = (t*21846) >> 16;
          const int co = t - 3*j;
          xTs[slot][co*SX + j] = (bf16)xv[k];
        }
      }
      if (i + 2 < fpb) {
        long fg = base + i + 2; if (fg >= B) fg = B - 1;
        #pragma unroll
        for (int k = 0; k < 4; ++k) { const int t = l + 64*k; if (t < 225) xv[k] = gx[fg*225 + t]; }
      }
    }
    __syncthreads();
  }
}

extern "C" void kernel_launch(void* const* d_in, const int* in_sizes, int n_in,
                              void* d_out, int out_size, void* d_ws, size_t ws_size,
                              hipStream_t stream) {
  const float* x  = (const float*)d_in[0];
  const float* A  = (const float*)d_in[1];
  const float* W1 = (const float*)d_in[2];
  const float* g1 = (const float*)d_in[3];
  const float* b1 = (const float*)d_in[4];
  const float* W2 = (const float*)d_in[5];
  const float* g2 = (const float*)d_in[6];
  const float* b2 = (const float*)d_in[7];
  const float* Wp = (const float*)d_in[8];
  const float* bp = (const float*)d_in[9];
  float* out = (float*)d_out;
  const int B = in_sizes[0] / 225;
  ke13<<<dim3(512), dim3(512), 0, stream>>>(x, A, W1, g1, b1, W2, g2, b2, Wp, bp, out, B);
}

// Round 15
// 224.929 us; speedup vs baseline: 1.1011x; 1.0090x over previous
//
#include <hip/hip_runtime.h>

typedef __bf16 bf16;
typedef __bf16 bf16x4 __attribute__((ext_vector_type(4)));
typedef __bf16 bf16x8 __attribute__((ext_vector_type(8)));
typedef float  f32x2  __attribute__((ext_vector_type(2)));
typedef float  f32x4  __attribute__((ext_vector_type(4)));
typedef unsigned int u32;
typedef u32 u32x2 __attribute__((ext_vector_type(2)));
typedef u32 u32x4 __attribute__((ext_vector_type(4)));
typedef unsigned short u16;

#define NJ 75
#define SA 104      // A_lds stride (bf16): 208B rows
#define SH 88       // h1 stride: 176B rows; k-overrun killed by A zero-cols
#define SG 136      // gss stride: 272B rows
#define SX 104      // xT stride
#define LN_EPS 1e-5f
#define MFMA16(a,b,c) __builtin_amdgcn_mfma_f32_16x16x32_bf16((a),(b),(c),0,0,0)

static __device__ __forceinline__ f32x4 f4z(){ f32x4 v={0.f,0.f,0.f,0.f}; return v; }
static __device__ __forceinline__ u32 pk2(float a, float b){
  u32 ua = (u32)__builtin_bit_cast(u16,(bf16)a);
  u32 ub = (u32)__builtin_bit_cast(u16,(bf16)b);
  return ua | (ub<<16);
}
static __device__ __forceinline__ float lo16f(u32 u){ return __uint_as_float(u<<16); }
static __device__ __forceinline__ float hi16f(u32 u){ return __uint_as_float(u & 0xffff0000u); }

template<int C>
static __device__ __forceinline__ float dppterm(float v){
  return __int_as_float(__builtin_amdgcn_update_dpp(0, __float_as_int(v), C, 0xF, 0xF, true));
}
static __device__ __forceinline__ float red16(float v){
  v += dppterm<0xB1>(v);
  v += dppterm<0x4E>(v);
  v += dppterm<0x141>(v);
  v += dppterm<0x140>(v);
  return v;
}

// launch_bounds(512,4): caps combined regs at 128 (arch 64 + acc 64) -> 16
// waves/CU with ~80KB LDS. Fastest operating point (R7/R11/R13). Do NOT relax.
__global__ __launch_bounds__(512, 4)
void ke14(const float* __restrict__ gx,  const float* __restrict__ gA,
          const float* __restrict__ gW1, const float* __restrict__ gg1, const float* __restrict__ gb1,
          const float* __restrict__ gW2, const float* __restrict__ gg2, const float* __restrict__ gb2,
          const float* __restrict__ gWp, const float* __restrict__ gbp,
          float* __restrict__ gout, int B)
{
  __shared__ __align__(16) bf16 A_lds[80*SA];       // 16,640 B (row 75 = ones: xbar trick)
  __shared__ __align__(16) bf16 h1[128*SH + 16];    // 22,560 B
  __shared__ __align__(16) bf16 gss[80*SG];         // 21,760 B
  __shared__ __align__(16) bf16 xTs[2][4*SX];       //  1,664 B (dbuf)
  __shared__ __align__(16) float red2[16*80*2];     // 10,240 B  [slot][j] f32 (s,q)
  __shared__ __align__(16) float fin[80*2];         //    640 B  (nm, rs)
  __shared__ __align__(16) float skl[2][256];       //  2,048 B (parity ring)
  __shared__ __align__(16) float b1l[128];          //    512 B
  __shared__ __align__(16) u32  g2b2[256];          //  1,024 B
  __shared__ __align__(16) bf16 W1l4[128*4];        //  1,024 B
  __shared__ __align__(16) u32x2 wpl[256];          //  2,048 B
  __shared__ __align__(16) float Msh[12];
  __shared__ float xbars[2][4];                     // written by w4 lane (0,11) in S_A

  const int tid = threadIdx.x;
  const int w   = tid >> 6;
  const int l   = tid & 63;
  const int l16 = l & 15;
  const int lg  = l >> 4;

  // ---------------- one-time init ----------------
  for (int i = tid; i < 80*SA; i += 512) {
    const int r = i / SA, c = i - r*SA;
    float v = 0.f;
    if (r < NJ && c < NJ) v = gA[r*NJ + c];
    else if (r == 75 && c < NJ) v = 1.f;   // ones-row: at-MFMA emits column sums of x at j=75
    A_lds[i] = (bf16)v;
  }
  for (int i = tid; i < 128*SH + 16; i += 512) h1[i] = (bf16)0.f;
  for (int i = tid; i < 2*4*SX; i += 512) ((bf16*)xTs)[i] = (bf16)0.f;
  float* wsc = red2;   // init scratch
  if (tid < 128) {
    wsc[tid*3+0] = gW1[tid*3+0];
    wsc[tid*3+1] = gW1[tid*3+1];
    wsc[tid*3+2] = gW1[tid*3+2];
    b1l[tid] = gb1[tid];
    fin[tid] = gg1[tid];          // g1 scratch
  }
  if (tid < 256) {
    g2b2[tid] = pk2(gg2[tid], gb2[tid]);
    u32x2 wv = { pk2(gWp[tid*3+0], gWp[tid*3+1]), pk2(gWp[tid*3+2], gbp[tid]) };
    wpl[tid] = wv;
  }
  __syncthreads();
  if (tid < 3) {
    float s = 0.f;
    for (int c = 0; c < 128; ++c) s += wsc[c*3 + tid];
    Msh[6 + tid] = s * (1.f/128.f);
  }
  __syncthreads();
  if (tid < 128) {
    float wt0 = wsc[tid*3+0] - Msh[6];
    float wt1 = wsc[tid*3+1] - Msh[7];
    float wt2 = wsc[tid*3+2] - Msh[8];
    const float g1v = fin[tid];
    W1l4[tid*4+0] = (bf16)(g1v*wt0);
    W1l4[tid*4+1] = (bf16)(g1v*wt1);
    W1l4[tid*4+2] = (bf16)(g1v*wt2);
    W1l4[tid*4+3] = (bf16)0.f;
    wsc[tid*3+0] = wt0; wsc[tid*3+1] = wt1; wsc[tid*3+2] = wt2;
  }
  __syncthreads();
  if (tid < 6) {
    const int pa[6] = {0,1,2,0,0,1};
    const int pb[6] = {0,1,2,1,2,2};
    float s = 0.f;
    for (int c = 0; c < 128; ++c) s += wsc[c*3 + pa[tid]] * wsc[c*3 + pb[tid]];
    Msh[tid] = s * (1.f/128.f);
  }

  bf16x8 W2fr[2][4];
  #pragma unroll
  for (int ot = 0; ot < 2; ++ot) {
    const int o = 16*(2*w + ot) + l16;
    #pragma unroll
    for (int ks = 0; ks < 4; ++ks) {
      bf16x8 v;
      #pragma unroll
      for (int e = 0; e < 8; ++e) v[e] = (bf16)gW2[o*128 + 32*ks + 8*lg + e];
      W2fr[ot][ks] = v;
    }
  }
  __syncthreads();
  const float M00 = Msh[0], M11 = Msh[1], M22 = Msh[2];
  const float M01 = Msh[3], M02 = Msh[4], M12 = Msh[5];

  const int  fpb  = (B + 511) >> 9;          // grid = 512
  const long base = (long)blockIdx.x * fpb;

  // prologue: wave5 loads + commits frame 0 (slot 0), then issues frame 1
  float xv[4] = {0.f, 0.f, 0.f, 0.f};
  if (w == 5) {
    long fg = base; if (fg >= B) fg = B - 1;
    #pragma unroll
    for (int k = 0; k < 4; ++k) { const int t = l + 64*k; if (t < 225) xv[k] = gx[fg*225 + t]; }
    #pragma unroll
    for (int k = 0; k < 4; ++k) {
      const int t = l + 64*k;
      if (t < 225) {
        const int j = (t*21846) >> 16;   // t/3
        const int co = t - 3*j;
        xTs[0][co*SX + j] = (bf16)xv[k];
      }
    }
    if (1 < fpb) {
      long f2 = base + 1; if (f2 >= B) f2 = B - 1;
      #pragma unroll
      for (int k = 0; k < 4; ++k) { const int t = l + 64*k; if (t < 225) xv[k] = gx[f2*225 + t]; }
    }
  }
  __syncthreads();

  f32x4 zacc[5][2];
  #pragma unroll
  for (int jt = 0; jt < 5; ++jt) { zacc[jt][0] = f4z(); zacc[jt][1] = f4z(); }

  const int nint = fpb + 2;
  for (int i = 0; i < nint; ++i) {
    // ==================== P1 ====================
    // S_B(i-1): g = A h1'  (c-slice = wave, all 8 waves)
    if (i >= 1 && i <= fpb) {
      const bf16* hb = &h1[(16*w + l16)*SH];
      bf16x8 hf0 = *(const bf16x8*)&hb[ 0 + 8*lg];
      bf16x8 hf1 = *(const bf16x8*)&hb[32 + 8*lg];
      bf16x8 hf2 = *(const bf16x8*)&hb[64 + 8*lg];  // overrun x A zero-cols = 0
      #pragma unroll
      for (int jt = 0; jt < 5; ++jt) {
        const bf16* ab = &A_lds[(16*jt + l16)*SA + 8*lg];
        f32x4 ag = f4z();
        ag = MFMA16(hf0, *(const bf16x8*)&ab[ 0], ag);
        ag = MFMA16(hf1, *(const bf16x8*)&ab[32], ag);
        ag = MFMA16(hf2, *(const bf16x8*)&ab[64], ag);
        bf16x4 p;
        #pragma unroll
        for (int r = 0; r < 4; ++r) p[r] = (bf16)ag[r];
        *(bf16x4*)&gss[(16*jt + l16)*SG + 16*w + 4*lg] = p;
      }
    }
    // w6 + w7: finalize LN2 stats for frame i-2: red2 -> fin
    if (w == 6 && i >= 2) {
      float S = 0.f, Q = 0.f;
      #pragma unroll
      for (int slot = 0; slot < 16; ++slot) {
        const f32x2 a = *(const f32x2*)&red2[(slot*80 + l)*2];
        S += a[0]; Q += a[1];
      }
      const float mu = S * (1.f/256.f);
      const float rs = rsqrtf(Q * (1.f/256.f) - mu*mu + LN_EPS);
      f32x2 nr = { -mu*rs, rs };
      *(f32x2*)&fin[l*2] = nr;
    }
    if (w == 7 && i >= 2 && l < 16) {
      const int j2 = 64 + l;
      float S = 0.f, Q = 0.f;
      #pragma unroll
      for (int slot = 0; slot < 16; ++slot) {
        const f32x2 a = *(const f32x2*)&red2[(slot*80 + j2)*2];
        S += a[0]; Q += a[1];
      }
      const float mu = S * (1.f/256.f);
      const float rs = rsqrtf(Q * (1.f/256.f) - mu*mu + LN_EPS);
      f32x2 nr = { -mu*rs, rs };
      *(f32x2*)&fin[j2*2] = nr;
    }
    // w7: skip(i-1) from xbars written by S_A(i-1)'s ones-row extraction
    if (w == 7 && i >= 1 && i-1 < fpb) {
      const int sp = (i-1) & 1;
      const float xb0 = xbars[sp][0], xb1 = xbars[sp][1], xb2 = xbars[sp][2];
      #pragma unroll
      for (int k = 0; k < 4; ++k) {
        const int o = l + 64*k;
        const u32x2 wv = wpl[o];
        skl[sp][o] = fmaf(lo16f(wv[0]), xb0, fmaf(hi16f(wv[0]), xb1, fmaf(lo16f(wv[1]), xb2, hi16f(wv[1]))));
      }
    }
    __syncthreads();

    // ==================== P2 ====================
    // wave 5 FIRST: commit xT(i+1) from regs, then ISSUE x(i+2) loads early so
    // HBM latency hides under wave5's own S_D+S_C below (not the barrier drain).
    if (w == 5 && i + 1 < fpb) {
      const int slot = (i+1) & 1;
      #pragma unroll
      for (int k = 0; k < 4; ++k) {
        const int t = l + 64*k;
        if (t < 225) {
          const int j = (t*21846) >> 16;
          const int co = t - 3*j;
          xTs[slot][co*SX + j] = (bf16)xv[k];
        }
      }
      if (i + 2 < fpb) {
        long fg = base + i + 2; if (fg >= B) fg = B - 1;
        #pragma unroll
        for (int k = 0; k < 4; ++k) { const int t = l + 64*k; if (t < 225) xv[k] = gx[fg*225 + t]; }
      }
    }
    // S_D(i-2): LN2 apply + mean + skip + store
    if (i >= 2) {
      float nmv[5], rsv[5];
      #pragma unroll
      for (int jt = 0; jt < 5; ++jt) {
        const f32x2 nr = *(const f32x2*)&fin[(16*jt + l16)*2];
        nmv[jt] = nr[0]; rsv[jt] = nr[1];
      }
      float os[2][4];
      #pragma unroll
      for (int ot = 0; ot < 2; ++ot) {
        const u32x4 gb = *(const u32x4*)&g2b2[16*(2*w + ot) + 4*lg];
        #pragma unroll
        for (int r = 0; r < 4; ++r) os[ot][r] = 0.f;
        #pragma unroll
        for (int jt = 0; jt < 5; ++jt) {
          #pragma unroll
          for (int r = 0; r < 4; ++r) {
            float v = fmaf(fmaf(zacc[jt][ot][r], rsv[jt], nmv[jt]), lo16f(gb[r]), hi16f(gb[r]));
            v = fmaxf(v, 0.f);
            if (jt == 4) v = (l16 < 11) ? v : 0.f;
            os[ot][r] += v;
          }
        }
        #pragma unroll
        for (int r = 0; r < 4; ++r) os[ot][r] = red16(os[ot][r]);
      }
      const long f = base + (i - 2);
      if (l16 == 0 && f < B) {
        #pragma unroll
        for (int ot = 0; ot < 2; ++ot) {
          const int o0 = 16*(2*w + ot) + 4*lg;
          const f32x4 sk = *(const f32x4*)&skl[(i-2)&1][o0];
          f32x4 res;
          #pragma unroll
          for (int r = 0; r < 4; ++r) res[r] = os[ot][r]*(1.f/NJ) + sk[r];
          *(f32x4*)&gout[f*256 + o0] = res;
        }
      }
    }
    // S_C(i-1): z = W2 g^T (o-slice = wave); xor16 + f32 partials
    if (i >= 1 && i <= fpb) {
      __builtin_amdgcn_s_setprio(1);
      #pragma unroll
      for (int jt = 0; jt < 5; ++jt) {
        const bf16* gr = &gss[(16*jt + l16)*SG + 8*lg];
        f32x4 z0 = f4z(), z1 = f4z();
        #pragma unroll
        for (int ks = 0; ks < 4; ++ks) {
          const bf16x8 gf = *(const bf16x8*)&gr[32*ks];
          z0 = MFMA16(W2fr[0][ks], gf, z0);
          z1 = MFMA16(W2fr[1][ks], gf, z1);
        }
        float s = 0.f, q = 0.f;
        #pragma unroll
        for (int r = 0; r < 4; ++r) {
          s += z0[r] + z1[r];
          q = fmaf(z0[r], z0[r], q); q = fmaf(z1[r], z1[r], q);
        }
        s += __shfl_xor(s, 16); q += __shfl_xor(q, 16);
        if ((lg & 1) == 0) {
          const int slot = 2*w + (lg >> 1);
          f32x2 sq = {s, q};
          *(f32x2*)&red2[(slot*80 + 16*jt + l16)*2] = sq;
        }
        zacc[jt][0] = z0; zacc[jt][1] = z1;
      }
      __builtin_amdgcn_s_setprio(0);
    }
    // S_A(i): x -> h1' (waves 0-4); analytic LN1; w4 extracts xbar from ones-row
    if (i < fpb && w < 5) {
      const int xrow = (l16 < 3) ? l16 : 3;
      const bf16* xb = &xTs[i&1][xrow*SX + 8*lg];
      const bf16* ab = &A_lds[(16*w + l16)*SA + 8*lg];
      f32x4 at = f4z();
      at = MFMA16(*(const bf16x8*)&xb[ 0], *(const bf16x8*)&ab[ 0], at);
      at = MFMA16(*(const bf16x8*)&xb[32], *(const bf16x8*)&ab[32], at);
      at = MFMA16(*(const bf16x8*)&xb[64], *(const bf16x8*)&ab[64], at);
      // ones-row extraction: wave 4, lane (lg==0,l16==11) holds j=75 = col-sums of x
      if (w == 4 && lg == 0 && l16 == 11) {
        xbars[i&1][0] = at[0] * (1.f/NJ);
        xbars[i&1][1] = at[1] * (1.f/NJ);
        xbars[i&1][2] = at[2] * (1.f/NJ);
      }
      const float a0 = at[0], a1 = at[1], a2 = at[2];
      float qd = fmaf(M00*a0, a0, fmaf(M11*a1, a1, fmaf(M22*a2, a2, LN_EPS)));
      qd = fmaf(2.f*M01*a0, a1, fmaf(2.f*M02*a0, a2, fmaf(2.f*M12*a1, a2, qd)));
      const float rs = rsqrtf(qd);
      bf16x8 hA;
      #pragma unroll
      for (int e = 0; e < 8; ++e) hA[e] = (bf16)0.f;
      hA[0] = (bf16)((lg == 0) ? a0*rs : 0.f);
      hA[1] = (bf16)((lg == 0) ? a1*rs : 0.f);
      hA[2] = (bf16)((lg == 0) ? a2*rs : 0.f);
      #pragma unroll
      for (int nt = 0; nt < 8; ++nt) {
        const bf16x4 w4v = *(const bf16x4*)&W1l4[(16*nt + l16)*4];
        bf16x8 wb;
        wb[0] = w4v[0]; wb[1] = w4v[1]; wb[2] = w4v[2]; wb[3] = w4v[3];
        wb[4] = w4v[3]; wb[5] = w4v[3]; wb[6] = w4v[3]; wb[7] = w4v[3];
        const f32x4 hp = MFMA16(hA, wb, f4z());
        const float b1v = b1l[16*nt + l16];
        bf16x4 pkk;
        #pragma unroll
        for (int r = 0; r < 4; ++r) pkk[r] = (bf16)fmaxf(hp[r] + b1v, 0.f);
        *(bf16x4*)&h1[(16*nt + l16)*SH + 16*w + 4*lg] = pkk;
      }
    }
    __syncthreads();
  }
}

extern "C" void kernel_launch(void* const* d_in, const int* in_sizes, int n_in,
                              void* d_out, int out_size, void* d_ws, size_t ws_size,
                              hipStream_t stream) {
  const float* x  = (const float*)d_in[0];
  const float* A  = (const float*)d_in[1];
  const float* W1 = (const float*)d_in[2];
  const float* g1 = (const float*)d_in[3];
  const float* b1 = (const float*)d_in[4];
  const float* W2 = (const float*)d_in[5];
  const float* g2 = (const float*)d_in[6];
  const float* b2 = (const float*)d_in[7];
  const float* Wp = (const float*)d_in[8];
  const float* bp = (const float*)d_in[9];
  float* out = (float*)d_out;
  const int B = in_sizes[0] / 225;
  ke14<<<dim3(512), dim3(512), 0, stream>>>(x, A, W1, g1, b1, W2, g2, b2, Wp, bp, out, B);
}